// Round 9
// baseline (134.015 us; speedup 1.0000x reference)
//
#include <hip/hip_runtime.h>
#include <math.h>

// Problem constants (B=4, H=8, P=196, D=64, NF=8, S=5)
#define BHP 6272   // B*H*P

// ---------------------------------------------------------------------------
// K1 (q and k merged): 16 rows per block, 320 threads (thread = output col o).
// ---------------------------------------------------------------------------
__global__ __launch_bounds__(320) void k1_lin_base(
    const float* __restrict__ qx, const float* __restrict__ kx,
    const float* __restrict__ Wq, const float* __restrict__ bq_,
    const float* __restrict__ Wk, const float* __restrict__ bk_,
    const float* __restrict__ BW,
    float* __restrict__ y5q, float* __restrict__ y5k,
    float* __restrict__ baseq, float* __restrict__ basek)
{
  const bool kside = blockIdx.x >= (BHP / 16);
  const float* x = kside ? kx : qx;
  const float* W = kside ? Wk : Wq;
  const float* bias = kside ? bk_ : bq_;
  float* y5 = kside ? y5k : y5q;
  float* basef = kside ? basek : baseq;
  const int r0 = (kside ? blockIdx.x - BHP / 16 : blockIdx.x) * 16;

  __shared__ float xs[16][64];    // 4 KB
  __shared__ float sy[16][320];   // 20 KB
  const int t = threadIdx.x;
  for (int idx = t; idx < 16 * 64; idx += 320)
    xs[idx >> 6][idx & 63] = x[(size_t)(r0 + (idx >> 6)) * 64 + (idx & 63)];
  __syncthreads();

  const int o = t;
  {
    const float* wrow = W + o * 64;
    float acc[16];
#pragma unroll
    for (int rr = 0; rr < 16; ++rr) acc[rr] = 0.f;
    for (int c = 0; c < 64; c += 4) {
      const float4 w4 = *reinterpret_cast<const float4*>(wrow + c);
#pragma unroll
      for (int rr = 0; rr < 16; ++rr) {
        const float4 x4 = *reinterpret_cast<const float4*>(&xs[rr][c]);
        acc[rr] += x4.x * w4.x + x4.y * w4.y + x4.z * w4.z + x4.w * w4.w;
      }
    }
    const float bb = bias[o];
#pragma unroll
    for (int rr = 0; rr < 16; ++rr) {
      const float y = acc[rr] + bb;
      y5[(size_t)(r0 + rr) * 320 + o] = y;
      sy[rr][o] = y / (1.f + __expf(-y));   // silu
    }
  }
  __syncthreads();
  {
    const int s = o >> 6, d = o & 63;
    const float* brow = BW + d * 64;
    float acc[16];
#pragma unroll
    for (int rr = 0; rr < 16; ++rr) acc[rr] = 0.f;
    for (int c = 0; c < 64; c += 4) {
      const float4 w4 = *reinterpret_cast<const float4*>(brow + c);
#pragma unroll
      for (int rr = 0; rr < 16; ++rr) {
        const float4 x4 = *reinterpret_cast<const float4*>(&sy[rr][s * 64 + c]);
        acc[rr] += x4.x * w4.x + x4.y * w4.y + x4.z * w4.z + x4.w * w4.w;
      }
    }
#pragma unroll
    for (int rr = 0; rr < 16; ++rr)
      basef[(size_t)(r0 + rr) * 320 + o] = acc[rr];
  }
}

// ---------------------------------------------------------------------------
// K2 (q/k merged): one wave per (side, bh, s2, p2); lane=d. coef in LDS.
// Writes a[idx] = sum_d sigmoid(...).
// ---------------------------------------------------------------------------
__global__ __launch_bounds__(1024) void k2_act(
    const float* __restrict__ y5q, const float* __restrict__ bq,
    const float* __restrict__ y5k, const float* __restrict__ bk,
    const float* __restrict__ gridI,
    const float* __restrict__ cq, const float* __restrict__ ck,
    const float* __restrict__ ssp, const float* __restrict__ sbase,
    float* __restrict__ aq, float* __restrict__ ak)
{
  __shared__ float cl[40][65];   // 10.2 KB, coef as [m][d], pad 65
  __shared__ float gli[40];
  const int t = threadIdx.x;
  const int wave = t >> 6, lane = t & 63;
  const int gi = blockIdx.x * 16 + wave;       // [0, 62720); side-uniform/block
  const bool kside = gi >= 31360;
  const int idx = kside ? gi - 31360 : gi;

  {
    const float* coef = kside ? ck : cq;       // uniform within block
    for (int e = t; e < 2560; e += 1024) {
      const int d = e / 40, r = e % 40;        // coef flat = d*40 + f*5 + s
      const int f = r / 5, s = r % 5;
      cl[s * 8 + f][d] = coef[e];              // coalesced read
    }
    if (t < 40) gli[t] = gridI[t];
  }
  __syncthreads();

  const int p2 = idx % 196;
  const int s2 = (idx / 196) % 5;
  const int bh = idx / 980;
  const int h = bh & 7;
  const int d = lane;
  const int i0 = s2 * 196 + p2;
  const float* y5 = kside ? y5k : y5q;
  const float* basef = kside ? bk : bq;
  const float basev =
      basef[(size_t)(bh * 196 + i0 / 5) * 320 + (i0 % 5) * 64 + d];

  const int j0 = s2 * 1568 + p2;
  int p = j0 / 40;
  int m = j0 % 40;
  const float* y5b = y5 + (size_t)bh * 196 * 320 + d;
  float fv = 0.f;
#pragma unroll
  for (int f2 = 0; f2 < 8; ++f2) {
    const float g = gli[m];                        // LDS broadcast
    const float qv = y5b[p * 320 + (m >> 3) * 64]; // coalesced global
    fv = fmaf(__sinf(g * qv), cl[m][d], fv);       // LDS conflict-free
    p += 4; m += 36;
    if (m >= 40) { m -= 40; p += 1; }              // j += 196 carry
  }
  const int so = ((h * 5 + s2) * 196 + p2) * 64 + d;
  const float v = fv * ssp[so] + basev * sbase[so];
  float sg = 1.f / (1.f + __expf(-v));
#pragma unroll
  for (int off = 32; off > 0; off >>= 1) sg += __shfl_xor(sg, off);
  if (lane == 0) (kside ? ak : aq)[idx] = sg;
}

// ---------------------------------------------------------------------------
// K2b: dense sin/cos table fill, all 64 lanes active.
//   tab[bh*7840 + m*196 + p] = {sin(g_m * a), cos(g_m * a)}, g_m = m+1 integer.
//   Integer-g identity: sin(g*a) = sin(g*(a mod 2pi)); Cody-Waite 2-word.
// ---------------------------------------------------------------------------
__global__ __launch_bounds__(256) void k2b_tab(
    const float* __restrict__ aq, const float* __restrict__ ak,
    const float* __restrict__ go, float2* __restrict__ tq,
    float2* __restrict__ tk)
{
  const int n = blockIdx.x * 256 + threadIdx.x;   // [0, 501760)
  const bool kside = n >= 250880;
  const int i2 = kside ? n - 250880 : n;
  const int p = i2 % 196;
  const int m = (i2 / 196) % 40;
  const int bh = i2 / 7840;
  const float g = rintf(go[m]);                   // integers 1..40
  const float a = (kside ? ak : aq)[bh * 980 + (m >> 3) * 196 + p];
  // r = a mod 2pi, |r| <= pi (a in (0, ~64), n0 <= 11)
  const float n0 = rintf(a * 0.15915494309f);
  float r = fmaf(n0, -6.28318548f, a);            // 2pi_hi (f32 nearest)
  r = fmaf(n0, 1.74845553e-7f, r);                // 2pi_lo correction
  const float u = g * r;                          // |u| <= 126 rad
  float2* tab = kside ? tk : tq;
  tab[bh * 7840 + m * 196 + p] = make_float2(__sinf(u), __cosf(u));
}

// ---------------------------------------------------------------------------
// K0t: coefficient transpose + cqo fusion. One block per i.
//   F[i*7840 + (s*8+f)*196 + j] = cqk[(i*196+j)*40 + f*5+s] * cqo[(s*196+i)*196+j]
// ---------------------------------------------------------------------------
__global__ __launch_bounds__(256) void k0_fuse(
    const float* __restrict__ cqk, const float* __restrict__ cqo,
    float* __restrict__ F)
{
  const int i = blockIdx.x;             // [0,196)
  const int t = threadIdx.x;
  __shared__ float ld[196 * 41];        // [j][e], pad 41: 32.1 KB
  const float4* src = reinterpret_cast<const float4*>(cqk + (size_t)i * 7840);
  for (int e4 = t; e4 < 1960; e4 += 256) {
    const float4 v = src[e4];           // coalesced
    const int flat = e4 * 4;
    const int j = flat / 40, m0 = flat % 40;   // 40%4==0: no row straddle
    float* dst = &ld[j * 41 + m0];
    dst[0] = v.x; dst[1] = v.y; dst[2] = v.z; dst[3] = v.w;
  }
  __syncthreads();
  for (int e = t; e < 7840; e += 256) {
    const int mq = e / 196, j = e % 196;       // mq = s*8+f
    const int s = mq >> 3, f = mq & 7;
    const float val = ld[j * 41 + f * 5 + s];  // stride 41: conflict-free
    F[(size_t)i * 7840 + e] = val * cqo[(s * 196 + i) * 196 + j];
  }
}

// ---------------------------------------------------------------------------
// K3 v6: XCD-locality streamer. row = i*32 + bh (i-major); bijective XCD
// swizzle gives each XCD a contiguous i-range: per-XCD working set =
// F slice (~0.77 MB) + tk (2 MB) + tq slice < 4 MB L2 -> L2-resident.
// wave = one (bh,i) row; 4 waves/block share the same F row (L1 hits).
// Zero barriers (sqs is same-wave LDS; lgkmcnt ordering suffices).
//   sin(g(aq+ak)) = sin(g aq)cos(g ak) + cos(g aq)sin(g ak)
// ---------------------------------------------------------------------------
__global__ __launch_bounds__(256, 6) void k3_outer(
    const float2* __restrict__ tq, const float2* __restrict__ tk,
    const float* __restrict__ F, float* __restrict__ out)
{
  const int t = threadIdx.x;
  const int wave = t >> 6, lane = t & 63;
  // 1568 blocks; swz = (bid%8)*196 + bid/8 is bijective (1568 % 8 == 0).
  const int bid = blockIdx.x;
  const int swz = (bid & 7) * 196 + (bid >> 3);
  const int row = swz * 4 + wave;          // row = i*32 + bh
  const int i = row >> 5;
  const int bh = row & 31;
  __shared__ float2 sqs[4][40];            // 1.3 KB; per-wave private slice

  if (lane < 40) sqs[wave][lane] = tq[(size_t)bh * 7840 + lane * 196 + i];
  // no barrier: sqs[wave] is written and read by the same wave only

  const float2* tkb = tk + (size_t)bh * 7840 + lane;
  const float* Fb = F + (size_t)i * 7840 + lane;
  float fj0 = 0.f, fj1 = 0.f, fj2 = 0.f, fj3 = 0.f;
#pragma unroll 4
  for (int mm = 0; mm < 40; ++mm) {
    const float2 sv = sqs[wave][mm];       // LDS broadcast
    const int o = mm * 196;
    const float2 kv0 = tkb[o];
    const float2 kv1 = tkb[o + 64];
    const float2 kv2 = tkb[o + 128];
    const float f0 = Fb[o];
    const float f1 = Fb[o + 64];
    const float f2 = Fb[o + 128];
    fj0 = fmaf((sv.x * kv0.y + sv.y * kv0.x), f0, fj0);
    fj1 = fmaf((sv.x * kv1.y + sv.y * kv1.x), f1, fj1);
    fj2 = fmaf((sv.x * kv2.y + sv.y * kv2.x), f2, fj2);
    if (lane < 4) {
      const float2 kv3 = tkb[o + 192];
      const float f3 = Fb[o + 192];
      fj3 = fmaf((sv.x * kv3.y + sv.y * kv3.x), f3, fj3);
    }
  }
  // in-wave softmax over the 196-wide row (lane<4 owns j=192+lane)
  const float fv3 = (lane < 4) ? fj3 : -INFINITY;
  float mx = fmaxf(fmaxf(fj0, fj1), fmaxf(fj2, fv3));
#pragma unroll
  for (int off = 32; off > 0; off >>= 1) mx = fmaxf(mx, __shfl_xor(mx, off));
  const float e0 = __expf(fj0 - mx);
  const float e1 = __expf(fj1 - mx);
  const float e2 = __expf(fj2 - mx);
  const float e3 = (lane < 4) ? __expf(fj3 - mx) : 0.f;
  float ss = e0 + e1 + e2 + e3;
#pragma unroll
  for (int off = 32; off > 0; off >>= 1) ss += __shfl_xor(ss, off);
  const float inv = 1.f / ss;
  float* op = out + (size_t)(bh * 196 + i) * 196 + lane;
  op[0] = e0 * inv;
  op[64] = e1 * inv;
  op[128] = e2 * inv;
  if (lane < 4) op[192] = e3 * inv;
}

// ---------------------------------------------------------------------------
extern "C" void kernel_launch(void* const* d_in, const int* in_sizes, int n_in,
                              void* d_out, int out_size, void* d_ws, size_t ws_size,
                              hipStream_t stream) {
  const float* q          = (const float*)d_in[0];
  const float* k          = (const float*)d_in[1];
  const float* grid       = (const float*)d_in[3];
  const float* grid_outer = (const float*)d_in[4];
  const float* base_w     = (const float*)d_in[5];
  const float* coef_q     = (const float*)d_in[6];
  const float* coef_k     = (const float*)d_in[7];
  const float* coef_qk    = (const float*)d_in[8];
  const float* scale_base = (const float*)d_in[9];
  const float* scale_sp   = (const float*)d_in[10];
  const float* cqo        = (const float*)d_in[11];
  const float* lqw        = (const float*)d_in[12];
  const float* lqb        = (const float*)d_in[13];
  const float* lkw        = (const float*)d_in[14];
  const float* lkb        = (const float*)d_in[15];
  float* out = (float*)d_out;

  const size_t SLAB = (size_t)BHP * 320;    // 2,007,040 floats
  float* q5 = (float*)d_ws;                 // [6272,320]
  float* k5 = q5 + SLAB;                    // [6272,320]
  float* bq = k5 + SLAB;                    // [6272,320]; reused as F (6.15MB)
  float* bk = bq + SLAB;                    // [6272,320]; reused as tabq+tabk
  float* aq = bk + SLAB;                    // [32,5,196]
  float* ak = aq + 32 * 5 * 196;            // [32,5,196]
  float* F = bq;                            // [196,40,196] after k2
  float2* tabq = (float2*)bk;               // [32*40*196] float2
  float2* tabk = tabq + 32 * 40 * 196;

  k1_lin_base<<<dim3(2 * BHP / 16), dim3(320), 0, stream>>>(
      q, k, lqw, lqb, lkw, lkb, base_w, q5, k5, bq, bk);
  k2_act<<<dim3(62720 / 16), dim3(1024), 0, stream>>>(
      q5, bq, k5, bk, grid, coef_q, coef_k, scale_sp, scale_base, aq, ak);
  k2b_tab<<<dim3(501760 / 256), dim3(256), 0, stream>>>(
      aq, ak, grid_outer, tabq, tabk);
  k0_fuse<<<dim3(196), dim3(256), 0, stream>>>(coef_qk, cqo, F);
  k3_outer<<<dim3(6272 / 4), dim3(256), 0, stream>>>(tabq, tabk, F, out);
}

// Round 10
// 131.654 us; speedup vs baseline: 1.0179x; 1.0179x over previous
//
#include <hip/hip_runtime.h>
#include <math.h>

// Problem constants (B=4, H=8, P=196, D=64, NF=8, S=5)
#define BHP 6272   // B*H*P

// ---------------------------------------------------------------------------
// K0w: pack weights for coalesced k1 loads.
//   Wq4/Wk4[c4*320 + o] = float4(W[o][4c4..4c4+3]);  BW4[c4*64 + d] likewise.
// ---------------------------------------------------------------------------
__global__ __launch_bounds__(256) void k0w_pack(
    const float* __restrict__ Wq, const float* __restrict__ Wk,
    const float* __restrict__ BW, float4* __restrict__ Wq4,
    float4* __restrict__ Wk4, float4* __restrict__ BW4)
{
  const int e = blockIdx.x * 256 + threadIdx.x;  // [0, 11264)
  if (e < 5120) {
    const int o = e % 320, c4 = e / 320;
    Wq4[e] = *reinterpret_cast<const float4*>(Wq + o * 64 + c4 * 4);
  } else if (e < 10240) {
    const int e2 = e - 5120;
    const int o = e2 % 320, c4 = e2 / 320;
    Wk4[e2] = *reinterpret_cast<const float4*>(Wk + o * 64 + c4 * 4);
  } else if (e < 11264) {
    const int e2 = e - 10240;
    const int d = e2 % 64, c4 = e2 / 64;
    BW4[e2] = *reinterpret_cast<const float4*>(BW + d * 64 + c4 * 4);
  }
}

// ---------------------------------------------------------------------------
// K1 v2: 8 rows/block (1568 blocks -> 7.7 waves/SIMD), packed-coalesced
// weight loads, LDS broadcasts for x/sy. thread = output col o.
// ---------------------------------------------------------------------------
__global__ __launch_bounds__(320) void k1_lin_base(
    const float* __restrict__ qx, const float* __restrict__ kx,
    const float4* __restrict__ Wq4, const float* __restrict__ bq_,
    const float4* __restrict__ Wk4, const float* __restrict__ bk_,
    const float4* __restrict__ BW4,
    float* __restrict__ y5q, float* __restrict__ y5k,
    float* __restrict__ baseq, float* __restrict__ basek)
{
  const bool kside = blockIdx.x >= (BHP / 8);
  const float* x = kside ? kx : qx;
  const float4* W4 = kside ? Wk4 : Wq4;
  const float* bias = kside ? bk_ : bq_;
  float* y5 = kside ? y5k : y5q;
  float* basef = kside ? basek : baseq;
  const int r0 = (kside ? blockIdx.x - BHP / 8 : blockIdx.x) * 8;

  __shared__ float xs[8][64];     // 2 KB
  __shared__ float sy[8][320];    // 10 KB
  const int t = threadIdx.x;
  for (int idx = t; idx < 8 * 64; idx += 320)
    xs[idx >> 6][idx & 63] = x[(size_t)(r0 + (idx >> 6)) * 64 + (idx & 63)];
  __syncthreads();

  const int o = t;
  {
    float acc[8];
#pragma unroll
    for (int rr = 0; rr < 8; ++rr) acc[rr] = 0.f;
#pragma unroll
    for (int c4 = 0; c4 < 16; ++c4) {
      const float4 w4 = W4[c4 * 320 + o];        // coalesced b128
#pragma unroll
      for (int rr = 0; rr < 8; ++rr) {
        const float4 x4 = *reinterpret_cast<const float4*>(&xs[rr][c4 * 4]);
        acc[rr] += x4.x * w4.x + x4.y * w4.y + x4.z * w4.z + x4.w * w4.w;
      }
    }
    const float bb = bias[o];
#pragma unroll
    for (int rr = 0; rr < 8; ++rr) {
      const float y = acc[rr] + bb;
      y5[(size_t)(r0 + rr) * 320 + o] = y;
      sy[rr][o] = y / (1.f + __expf(-y));        // silu
    }
  }
  __syncthreads();
  {
    const int s = o >> 6, d = o & 63;            // s uniform per wave
    float acc[8];
#pragma unroll
    for (int rr = 0; rr < 8; ++rr) acc[rr] = 0.f;
#pragma unroll
    for (int c4 = 0; c4 < 16; ++c4) {
      const float4 w4 = BW4[c4 * 64 + d];        // coalesced b128
#pragma unroll
      for (int rr = 0; rr < 8; ++rr) {
        const float4 x4 =
            *reinterpret_cast<const float4*>(&sy[rr][s * 64 + c4 * 4]);
        acc[rr] += x4.x * w4.x + x4.y * w4.y + x4.z * w4.z + x4.w * w4.w;
      }
    }
#pragma unroll
    for (int rr = 0; rr < 8; ++rr)
      basef[(size_t)(r0 + rr) * 320 + o] = acc[rr];
  }
}

// ---------------------------------------------------------------------------
// K2 (q/k merged): one wave per (side, bh, s2, p2); lane=d. coef in LDS.
// Writes a[idx] = sum_d sigmoid(...).
// ---------------------------------------------------------------------------
__global__ __launch_bounds__(1024) void k2_act(
    const float* __restrict__ y5q, const float* __restrict__ bq,
    const float* __restrict__ y5k, const float* __restrict__ bk,
    const float* __restrict__ gridI,
    const float* __restrict__ cq, const float* __restrict__ ck,
    const float* __restrict__ ssp, const float* __restrict__ sbase,
    float* __restrict__ aq, float* __restrict__ ak)
{
  __shared__ float cl[40][65];   // 10.2 KB, coef as [m][d], pad 65
  __shared__ float gli[40];
  const int t = threadIdx.x;
  const int wave = t >> 6, lane = t & 63;
  const int gi = blockIdx.x * 16 + wave;       // [0, 62720); side-uniform/block
  const bool kside = gi >= 31360;
  const int idx = kside ? gi - 31360 : gi;

  {
    const float* coef = kside ? ck : cq;       // uniform within block
    for (int e = t; e < 2560; e += 1024) {
      const int d = e / 40, r = e % 40;        // coef flat = d*40 + f*5 + s
      const int f = r / 5, s = r % 5;
      cl[s * 8 + f][d] = coef[e];              // coalesced read
    }
    if (t < 40) gli[t] = gridI[t];
  }
  __syncthreads();

  const int p2 = idx % 196;
  const int s2 = (idx / 196) % 5;
  const int bh = idx / 980;
  const int h = bh & 7;
  const int d = lane;
  const int i0 = s2 * 196 + p2;
  const float* y5 = kside ? y5k : y5q;
  const float* basef = kside ? bk : bq;
  const float basev =
      basef[(size_t)(bh * 196 + i0 / 5) * 320 + (i0 % 5) * 64 + d];

  const int j0 = s2 * 1568 + p2;
  int p = j0 / 40;
  int m = j0 % 40;
  const float* y5b = y5 + (size_t)bh * 196 * 320 + d;
  float fv = 0.f;
#pragma unroll
  for (int f2 = 0; f2 < 8; ++f2) {
    const float g = gli[m];                        // LDS broadcast
    const float qv = y5b[p * 320 + (m >> 3) * 64]; // coalesced global
    fv = fmaf(__sinf(g * qv), cl[m][d], fv);       // LDS conflict-free
    p += 4; m += 36;
    if (m >= 40) { m -= 40; p += 1; }              // j += 196 carry
  }
  const int so = ((h * 5 + s2) * 196 + p2) * 64 + d;
  const float v = fv * ssp[so] + basev * sbase[so];
  float sg = 1.f / (1.f + __expf(-v));
#pragma unroll
  for (int off = 32; off > 0; off >>= 1) sg += __shfl_xor(sg, off);
  if (lane == 0) (kside ? ak : aq)[idx] = sg;
}

// ---------------------------------------------------------------------------
// K2b: dense sin/cos table fill, all 64 lanes active.
//   tab[bh*7840 + m*196 + p] = {sin(g_m * a), cos(g_m * a)}, g_m = m+1 integer.
//   Integer-g identity: sin(g*a) = sin(g*(a mod 2pi)); Cody-Waite 2-word.
// ---------------------------------------------------------------------------
__global__ __launch_bounds__(256) void k2b_tab(
    const float* __restrict__ aq, const float* __restrict__ ak,
    const float* __restrict__ go, float2* __restrict__ tq,
    float2* __restrict__ tk)
{
  const int n = blockIdx.x * 256 + threadIdx.x;   // [0, 501760)
  const bool kside = n >= 250880;
  const int i2 = kside ? n - 250880 : n;
  const int p = i2 % 196;
  const int m = (i2 / 196) % 40;
  const int bh = i2 / 7840;
  const float g = rintf(go[m]);                   // integers 1..40
  const float a = (kside ? ak : aq)[bh * 980 + (m >> 3) * 196 + p];
  // r = a mod 2pi, |r| <= pi (a in (0, ~64), n0 <= 11)
  const float n0 = rintf(a * 0.15915494309f);
  float r = fmaf(n0, -6.28318548f, a);            // 2pi_hi (f32 nearest)
  r = fmaf(n0, 1.74845553e-7f, r);                // 2pi_lo correction
  const float u = g * r;                          // |u| <= 126 rad
  float2* tab = kside ? tk : tq;
  tab[bh * 7840 + m * 196 + p] = make_float2(__sinf(u), __cosf(u));
}

// ---------------------------------------------------------------------------
// K0t: coefficient transpose + cqo fusion. One block per i.
//   F[i*7840 + (s*8+f)*196 + j] = cqk[(i*196+j)*40 + f*5+s] * cqo[(s*196+i)*196+j]
// ---------------------------------------------------------------------------
__global__ __launch_bounds__(256) void k0_fuse(
    const float* __restrict__ cqk, const float* __restrict__ cqo,
    float* __restrict__ F)
{
  const int i = blockIdx.x;             // [0,196)
  const int t = threadIdx.x;
  __shared__ float ld[196 * 41];        // [j][e], pad 41: 32.1 KB
  const float4* src = reinterpret_cast<const float4*>(cqk + (size_t)i * 7840);
  for (int e4 = t; e4 < 1960; e4 += 256) {
    const float4 v = src[e4];           // coalesced
    const int flat = e4 * 4;
    const int j = flat / 40, m0 = flat % 40;   // 40%4==0: no row straddle
    float* dst = &ld[j * 41 + m0];
    dst[0] = v.x; dst[1] = v.y; dst[2] = v.z; dst[3] = v.w;
  }
  __syncthreads();
  for (int e = t; e < 7840; e += 256) {
    const int mq = e / 196, j = e % 196;       // mq = s*8+f
    const int s = mq >> 3, f = mq & 7;
    const float val = ld[j * 41 + f * 5 + s];  // stride 41: conflict-free
    F[(size_t)i * 7840 + e] = val * cqo[(s * 196 + i) * 196 + j];
  }
}

// ---------------------------------------------------------------------------
// K3 v6: XCD-locality streamer. row = i*32 + bh (i-major); bijective XCD
// swizzle gives each XCD a contiguous i-range -> per-XCD working set
// (F slice + tk + tq slice) < 4 MB L2. wave = one (bh,i) row; zero barriers.
//   sin(g(aq+ak)) = sin(g aq)cos(g ak) + cos(g aq)sin(g ak)
// ---------------------------------------------------------------------------
__global__ __launch_bounds__(256, 6) void k3_outer(
    const float2* __restrict__ tq, const float2* __restrict__ tk,
    const float* __restrict__ F, float* __restrict__ out)
{
  const int t = threadIdx.x;
  const int wave = t >> 6, lane = t & 63;
  // 1568 blocks; swz = (bid%8)*196 + bid/8 is bijective (1568 % 8 == 0).
  const int bid = blockIdx.x;
  const int swz = (bid & 7) * 196 + (bid >> 3);
  const int row = swz * 4 + wave;          // row = i*32 + bh
  const int i = row >> 5;
  const int bh = row & 31;
  __shared__ float2 sqs[4][40];            // 1.3 KB; per-wave private slice

  if (lane < 40) sqs[wave][lane] = tq[(size_t)bh * 7840 + lane * 196 + i];
  // no barrier: sqs[wave] is written and read by the same wave only

  const float2* tkb = tk + (size_t)bh * 7840 + lane;
  const float* Fb = F + (size_t)i * 7840 + lane;
  float fj0 = 0.f, fj1 = 0.f, fj2 = 0.f, fj3 = 0.f;
#pragma unroll 4
  for (int mm = 0; mm < 40; ++mm) {
    const float2 sv = sqs[wave][mm];       // LDS broadcast
    const int o = mm * 196;
    const float2 kv0 = tkb[o];
    const float2 kv1 = tkb[o + 64];
    const float2 kv2 = tkb[o + 128];
    const float f0 = Fb[o];
    const float f1 = Fb[o + 64];
    const float f2 = Fb[o + 128];
    fj0 = fmaf((sv.x * kv0.y + sv.y * kv0.x), f0, fj0);
    fj1 = fmaf((sv.x * kv1.y + sv.y * kv1.x), f1, fj1);
    fj2 = fmaf((sv.x * kv2.y + sv.y * kv2.x), f2, fj2);
    if (lane < 4) {
      const float2 kv3 = tkb[o + 192];
      const float f3 = Fb[o + 192];
      fj3 = fmaf((sv.x * kv3.y + sv.y * kv3.x), f3, fj3);
    }
  }
  // in-wave softmax over the 196-wide row (lane<4 owns j=192+lane)
  const float fv3 = (lane < 4) ? fj3 : -INFINITY;
  float mx = fmaxf(fmaxf(fj0, fj1), fmaxf(fj2, fv3));
#pragma unroll
  for (int off = 32; off > 0; off >>= 1) mx = fmaxf(mx, __shfl_xor(mx, off));
  const float e0 = __expf(fj0 - mx);
  const float e1 = __expf(fj1 - mx);
  const float e2 = __expf(fj2 - mx);
  const float e3 = (lane < 4) ? __expf(fj3 - mx) : 0.f;
  float ss = e0 + e1 + e2 + e3;
#pragma unroll
  for (int off = 32; off > 0; off >>= 1) ss += __shfl_xor(ss, off);
  const float inv = 1.f / ss;
  float* op = out + (size_t)(bh * 196 + i) * 196 + lane;
  op[0] = e0 * inv;
  op[64] = e1 * inv;
  op[128] = e2 * inv;
  if (lane < 4) op[192] = e3 * inv;
}

// ---------------------------------------------------------------------------
extern "C" void kernel_launch(void* const* d_in, const int* in_sizes, int n_in,
                              void* d_out, int out_size, void* d_ws, size_t ws_size,
                              hipStream_t stream) {
  const float* q          = (const float*)d_in[0];
  const float* k          = (const float*)d_in[1];
  const float* grid       = (const float*)d_in[3];
  const float* grid_outer = (const float*)d_in[4];
  const float* base_w     = (const float*)d_in[5];
  const float* coef_q     = (const float*)d_in[6];
  const float* coef_k     = (const float*)d_in[7];
  const float* coef_qk    = (const float*)d_in[8];
  const float* scale_base = (const float*)d_in[9];
  const float* scale_sp   = (const float*)d_in[10];
  const float* cqo        = (const float*)d_in[11];
  const float* lqw        = (const float*)d_in[12];
  const float* lqb        = (const float*)d_in[13];
  const float* lkw        = (const float*)d_in[14];
  const float* lkb        = (const float*)d_in[15];
  float* out = (float*)d_out;

  const size_t SLAB = (size_t)BHP * 320;    // 2,007,040 floats
  float* q5 = (float*)d_ws;                 // [6272,320]
  float* k5 = q5 + SLAB;                    // [6272,320]
  float* bq = k5 + SLAB;                    // [6272,320]; reused as F (6.15MB)
  float* bk = bq + SLAB;                    // [6272,320]; reused as tabq+tabk
  float* aq = bk + SLAB;                    // [32,5,196]
  float* ak = aq + 32 * 5 * 196;            // [32,5,196]
  float* wpack = ak + 32 * 5 * 196;         // 5120+5120+1024 float4
  float4* Wq4 = (float4*)wpack;
  float4* Wk4 = Wq4 + 5120;
  float4* BW4 = Wk4 + 5120;
  float* F = bq;                            // [196,40,196] after k2
  float2* tabq = (float2*)bk;               // [32*40*196] float2
  float2* tabk = tabq + 32 * 40 * 196;

  k0w_pack<<<dim3(44), dim3(256), 0, stream>>>(lqw, lkw, base_w, Wq4, Wk4, BW4);
  k1_lin_base<<<dim3(2 * BHP / 8), dim3(320), 0, stream>>>(
      q, k, Wq4, lqb, Wk4, lkb, BW4, q5, k5, bq, bk);
  k2_act<<<dim3(62720 / 16), dim3(1024), 0, stream>>>(
      q5, bq, k5, bk, grid, coef_q, coef_k, scale_sp, scale_base, aq, ak);
  k2b_tab<<<dim3(501760 / 256), dim3(256), 0, stream>>>(
      aq, ak, grid_outer, tabq, tabk);
  k0_fuse<<<dim3(196), dim3(256), 0, stream>>>(coef_qk, cqo, F);
  k3_outer<<<dim3(6272 / 4), dim3(256), 0, stream>>>(tabq, tabk, F, out);
}

// Round 11
// 114.241 us; speedup vs baseline: 1.1731x; 1.1524x over previous
//
#include <hip/hip_runtime.h>
#include <math.h>

// Problem constants (B=4, H=8, P=196, D=64, NF=8, S=5)
#define BHP 6272   // B*H*P

// ---------------------------------------------------------------------------
// K0w: pack weights for coalesced k1 loads.
//   Wq4/Wk4[c4*320 + o] = float4(W[o][4c4..4c4+3]);  BW4[c4*64 + d] likewise.
// ---------------------------------------------------------------------------
__global__ __launch_bounds__(256) void k0w_pack(
    const float* __restrict__ Wq, const float* __restrict__ Wk,
    const float* __restrict__ BW, float4* __restrict__ Wq4,
    float4* __restrict__ Wk4, float4* __restrict__ BW4)
{
  const int e = blockIdx.x * 256 + threadIdx.x;  // [0, 11264)
  if (e < 5120) {
    const int o = e % 320, c4 = e / 320;
    Wq4[e] = *reinterpret_cast<const float4*>(Wq + o * 64 + c4 * 4);
  } else if (e < 10240) {
    const int e2 = e - 5120;
    const int o = e2 % 320, c4 = e2 / 320;
    Wk4[e2] = *reinterpret_cast<const float4*>(Wk + o * 64 + c4 * 4);
  } else if (e < 11264) {
    const int e2 = e - 10240;
    const int d = e2 % 64, c4 = e2 / 64;
    BW4[e2] = *reinterpret_cast<const float4*>(BW + d * 64 + c4 * 4);
  }
}

// ---------------------------------------------------------------------------
// K1 v3: weights preloaded into a register array (one vmcnt wait), explicit
// fmaf chains. 8 rows/block, 320 threads (thread = output col o).
// ---------------------------------------------------------------------------
__global__ __launch_bounds__(320) void k1_lin_base(
    const float* __restrict__ qx, const float* __restrict__ kx,
    const float4* __restrict__ Wq4, const float* __restrict__ bq_,
    const float4* __restrict__ Wk4, const float* __restrict__ bk_,
    const float4* __restrict__ BW4,
    float* __restrict__ y5q, float* __restrict__ y5k,
    float* __restrict__ baseq, float* __restrict__ basek)
{
  const bool kside = blockIdx.x >= (BHP / 8);
  const float* x = kside ? kx : qx;
  const float4* W4 = kside ? Wk4 : Wq4;
  const float* bias = kside ? bk_ : bq_;
  float* y5 = kside ? y5k : y5q;
  float* basef = kside ? basek : baseq;
  const int r0 = (kside ? blockIdx.x - BHP / 8 : blockIdx.x) * 8;

  __shared__ float xs[8][64];     // 2 KB
  __shared__ float sy[8][320];    // 10 KB
  const int t = threadIdx.x;
  for (int idx = t; idx < 8 * 64; idx += 320)
    xs[idx >> 6][idx & 63] = x[(size_t)(r0 + (idx >> 6)) * 64 + (idx & 63)];
  __syncthreads();

  const int o = t;
  float4 w[16];
  {
#pragma unroll
    for (int c4 = 0; c4 < 16; ++c4) w[c4] = W4[c4 * 320 + o];  // 16 b128, batched
    float acc[8];
#pragma unroll
    for (int rr = 0; rr < 8; ++rr) acc[rr] = 0.f;
#pragma unroll
    for (int c4 = 0; c4 < 16; ++c4) {
#pragma unroll
      for (int rr = 0; rr < 8; ++rr) {
        const float4 x4 = *reinterpret_cast<const float4*>(&xs[rr][c4 * 4]);
        acc[rr] = fmaf(x4.x, w[c4].x, acc[rr]);
        acc[rr] = fmaf(x4.y, w[c4].y, acc[rr]);
        acc[rr] = fmaf(x4.z, w[c4].z, acc[rr]);
        acc[rr] = fmaf(x4.w, w[c4].w, acc[rr]);
      }
    }
    const float bb = bias[o];
#pragma unroll
    for (int rr = 0; rr < 8; ++rr) {
      const float y = acc[rr] + bb;
      y5[(size_t)(r0 + rr) * 320 + o] = y;
      sy[rr][o] = y / (1.f + __expf(-y));        // silu
    }
  }
  __syncthreads();
  {
    const int s = o >> 6, d = o & 63;            // s uniform per wave
#pragma unroll
    for (int c4 = 0; c4 < 16; ++c4) w[c4] = BW4[c4 * 64 + d];
    float acc[8];
#pragma unroll
    for (int rr = 0; rr < 8; ++rr) acc[rr] = 0.f;
#pragma unroll
    for (int c4 = 0; c4 < 16; ++c4) {
#pragma unroll
      for (int rr = 0; rr < 8; ++rr) {
        const float4 x4 =
            *reinterpret_cast<const float4*>(&sy[rr][s * 64 + c4 * 4]);
        acc[rr] = fmaf(x4.x, w[c4].x, acc[rr]);
        acc[rr] = fmaf(x4.y, w[c4].y, acc[rr]);
        acc[rr] = fmaf(x4.z, w[c4].z, acc[rr]);
        acc[rr] = fmaf(x4.w, w[c4].w, acc[rr]);
      }
    }
#pragma unroll
    for (int rr = 0; rr < 8; ++rr)
      basef[(size_t)(r0 + rr) * 320 + o] = acc[rr];
  }
}

// ---------------------------------------------------------------------------
// K2 (q/k merged): one wave per (side, bh, s2, p2); lane=d. coef in LDS.
// Writes a[idx] = sum_d sigmoid(...).
// ---------------------------------------------------------------------------
__global__ __launch_bounds__(1024) void k2_act(
    const float* __restrict__ y5q, const float* __restrict__ bq,
    const float* __restrict__ y5k, const float* __restrict__ bk,
    const float* __restrict__ gridI,
    const float* __restrict__ cq, const float* __restrict__ ck,
    const float* __restrict__ ssp, const float* __restrict__ sbase,
    float* __restrict__ aq, float* __restrict__ ak)
{
  __shared__ float cl[40][65];   // 10.2 KB, coef as [m][d], pad 65
  __shared__ float gli[40];
  const int t = threadIdx.x;
  const int wave = t >> 6, lane = t & 63;
  const int gi = blockIdx.x * 16 + wave;       // [0, 62720); side-uniform/block
  const bool kside = gi >= 31360;
  const int idx = kside ? gi - 31360 : gi;

  {
    const float* coef = kside ? ck : cq;       // uniform within block
    for (int e = t; e < 2560; e += 1024) {
      const int d = e / 40, r = e % 40;        // coef flat = d*40 + f*5 + s
      const int f = r / 5, s = r % 5;
      cl[s * 8 + f][d] = coef[e];              // coalesced read
    }
    if (t < 40) gli[t] = gridI[t];
  }
  __syncthreads();

  const int p2 = idx % 196;
  const int s2 = (idx / 196) % 5;
  const int bh = idx / 980;
  const int h = bh & 7;
  const int d = lane;
  const int i0 = s2 * 196 + p2;
  const float* y5 = kside ? y5k : y5q;
  const float* basef = kside ? bk : bq;
  const float basev =
      basef[(size_t)(bh * 196 + i0 / 5) * 320 + (i0 % 5) * 64 + d];

  const int j0 = s2 * 1568 + p2;
  int p = j0 / 40;
  int m = j0 % 40;
  const float* y5b = y5 + (size_t)bh * 196 * 320 + d;
  float fv = 0.f;
#pragma unroll
  for (int f2 = 0; f2 < 8; ++f2) {
    const float g = gli[m];                        // LDS broadcast
    const float qv = y5b[p * 320 + (m >> 3) * 64]; // coalesced global
    fv = fmaf(__sinf(g * qv), cl[m][d], fv);       // LDS conflict-free
    p += 4; m += 36;
    if (m >= 40) { m -= 40; p += 1; }              // j += 196 carry
  }
  const int so = ((h * 5 + s2) * 196 + p2) * 64 + d;
  const float v = fv * ssp[so] + basev * sbase[so];
  float sg = 1.f / (1.f + __expf(-v));
#pragma unroll
  for (int off = 32; off > 0; off >>= 1) sg += __shfl_xor(sg, off);
  if (lane == 0) (kside ? ak : aq)[idx] = sg;
}

// ---------------------------------------------------------------------------
// K2b: dense sin/cos table fill, all 64 lanes active.
//   tab[bh*7840 + m*196 + p] = {sin(g_m * a), cos(g_m * a)}, g_m = m+1 integer.
//   Integer-g identity: sin(g*a) = sin(g*(a mod 2pi)); Cody-Waite 2-word.
// ---------------------------------------------------------------------------
__global__ __launch_bounds__(256) void k2b_tab(
    const float* __restrict__ aq, const float* __restrict__ ak,
    const float* __restrict__ go, float2* __restrict__ tq,
    float2* __restrict__ tk)
{
  const int n = blockIdx.x * 256 + threadIdx.x;   // [0, 501760)
  const bool kside = n >= 250880;
  const int i2 = kside ? n - 250880 : n;
  const int p = i2 % 196;
  const int m = (i2 / 196) % 40;
  const int bh = i2 / 7840;
  const float g = rintf(go[m]);                   // integers 1..40
  const float a = (kside ? ak : aq)[bh * 980 + (m >> 3) * 196 + p];
  // r = a mod 2pi, |r| <= pi (a in (0, ~64), n0 <= 11)
  const float n0 = rintf(a * 0.15915494309f);
  float r = fmaf(n0, -6.28318548f, a);            // 2pi_hi (f32 nearest)
  r = fmaf(n0, 1.74845553e-7f, r);                // 2pi_lo correction
  const float u = g * r;                          // |u| <= 126 rad
  float2* tab = kside ? tk : tq;
  tab[bh * 7840 + m * 196 + p] = make_float2(__sinf(u), __cosf(u));
}

// ---------------------------------------------------------------------------
// K0t: coefficient transpose + cqo fusion. One block per i.
//   F[i*7840 + (s*8+f)*196 + j] = cqk[(i*196+j)*40 + f*5+s] * cqo[(s*196+i)*196+j]
// ---------------------------------------------------------------------------
__global__ __launch_bounds__(256) void k0_fuse(
    const float* __restrict__ cqk, const float* __restrict__ cqo,
    float* __restrict__ F)
{
  const int i = blockIdx.x;             // [0,196)
  const int t = threadIdx.x;
  __shared__ float ld[196 * 41];        // [j][e], pad 41: 32.1 KB
  const float4* src = reinterpret_cast<const float4*>(cqk + (size_t)i * 7840);
  for (int e4 = t; e4 < 1960; e4 += 256) {
    const float4 v = src[e4];           // coalesced
    const int flat = e4 * 4;
    const int j = flat / 40, m0 = flat % 40;   // 40%4==0: no row straddle
    float* dst = &ld[j * 41 + m0];
    dst[0] = v.x; dst[1] = v.y; dst[2] = v.z; dst[3] = v.w;
  }
  __syncthreads();
  for (int e = t; e < 7840; e += 256) {
    const int mq = e / 196, j = e % 196;       // mq = s*8+f
    const int s = mq >> 3, f = mq & 7;
    const float val = ld[j * 41 + f * 5 + s];  // stride 41: conflict-free
    F[(size_t)i * 7840 + e] = val * cqo[(s * 196 + i) * 196 + j];
  }
}

// ---------------------------------------------------------------------------
// K3 v7: block = (i, 4-bh group). F row i staged to LDS once (4 waves share);
// VMEM per wave halves to ~130 b64 tk loads (F now on the LGKM pipe).
// XCD swizzle keeps i-ranges contiguous per XCD (F slice + tk L2-resident).
// In-wave softmax, single barrier, no VGPR squeeze.
//   sin(g(aq+ak)) = sin(g aq)cos(g ak) + cos(g aq)sin(g ak)
// ---------------------------------------------------------------------------
__global__ __launch_bounds__(256) void k3_outer(
    const float2* __restrict__ tq, const float2* __restrict__ tk,
    const float* __restrict__ F, float* __restrict__ out)
{
  const int t = threadIdx.x;
  const int wave = t >> 6, lane = t & 63;
  // 1568 blocks; swz = (bid%8)*196 + bid/8 bijective (1568 % 8 == 0).
  // XCD x gets swz in [x*196,(x+1)*196) -> i in a contiguous ~24.5 range.
  const int bid = blockIdx.x;
  const int swz = (bid & 7) * 196 + (bid >> 3);
  const int i = swz >> 3;                  // [0,196)
  const int bhg = swz & 7;                 // [0,8)
  const int bh = bhg * 4 + wave;
  __shared__ float fs[7840];               // 31.4 KB: F row i, [m][j]
  __shared__ float2 sqs[4][40];            // 1.3 KB

  {
    const float4* Fp = reinterpret_cast<const float4*>(F + (size_t)i * 7840);
    float4* fs4 = reinterpret_cast<float4*>(fs);
    for (int e = t; e < 1960; e += 256) fs4[e] = Fp[e];   // coalesced
    if (lane < 40) sqs[wave][lane] = tq[(size_t)bh * 7840 + lane * 196 + i];
  }
  __syncthreads();                          // the only barrier

  const float2* tkb = tk + (size_t)bh * 7840 + lane;
  const float* fsl = fs + lane;
  float fj0 = 0.f, fj1 = 0.f, fj2 = 0.f, fj3 = 0.f;
#pragma unroll 4
  for (int mm = 0; mm < 40; ++mm) {
    const float2 sv = sqs[wave][mm];       // LDS broadcast
    const int o = mm * 196;
    const float2 kv0 = tkb[o];
    const float2 kv1 = tkb[o + 64];
    const float2 kv2 = tkb[o + 128];
    fj0 = fmaf(sv.x * kv0.y + sv.y * kv0.x, fsl[o], fj0);
    fj1 = fmaf(sv.x * kv1.y + sv.y * kv1.x, fsl[o + 64], fj1);
    fj2 = fmaf(sv.x * kv2.y + sv.y * kv2.x, fsl[o + 128], fj2);
    if (lane < 4) {
      const float2 kv3 = tkb[o + 192];
      fj3 = fmaf(sv.x * kv3.y + sv.y * kv3.x, fsl[o + 192], fj3);
    }
  }
  // in-wave softmax over the 196-wide row (lane<4 owns j=192+lane)
  const float fv3 = (lane < 4) ? fj3 : -INFINITY;
  float mx = fmaxf(fmaxf(fj0, fj1), fmaxf(fj2, fv3));
#pragma unroll
  for (int off = 32; off > 0; off >>= 1) mx = fmaxf(mx, __shfl_xor(mx, off));
  const float e0 = __expf(fj0 - mx);
  const float e1 = __expf(fj1 - mx);
  const float e2 = __expf(fj2 - mx);
  const float e3 = (lane < 4) ? __expf(fj3 - mx) : 0.f;
  float ss = e0 + e1 + e2 + e3;
#pragma unroll
  for (int off = 32; off > 0; off >>= 1) ss += __shfl_xor(ss, off);
  const float inv = 1.f / ss;
  float* op = out + (size_t)(bh * 196 + i) * 196 + lane;
  op[0] = e0 * inv;
  op[64] = e1 * inv;
  op[128] = e2 * inv;
  if (lane < 4) op[192] = e3 * inv;
}

// ---------------------------------------------------------------------------
extern "C" void kernel_launch(void* const* d_in, const int* in_sizes, int n_in,
                              void* d_out, int out_size, void* d_ws, size_t ws_size,
                              hipStream_t stream) {
  const float* q          = (const float*)d_in[0];
  const float* k          = (const float*)d_in[1];
  const float* grid       = (const float*)d_in[3];
  const float* grid_outer = (const float*)d_in[4];
  const float* base_w     = (const float*)d_in[5];
  const float* coef_q     = (const float*)d_in[6];
  const float* coef_k     = (const float*)d_in[7];
  const float* coef_qk    = (const float*)d_in[8];
  const float* scale_base = (const float*)d_in[9];
  const float* scale_sp   = (const float*)d_in[10];
  const float* cqo        = (const float*)d_in[11];
  const float* lqw        = (const float*)d_in[12];
  const float* lqb        = (const float*)d_in[13];
  const float* lkw        = (const float*)d_in[14];
  const float* lkb        = (const float*)d_in[15];
  float* out = (float*)d_out;

  const size_t SLAB = (size_t)BHP * 320;    // 2,007,040 floats
  float* q5 = (float*)d_ws;                 // [6272,320]
  float* k5 = q5 + SLAB;                    // [6272,320]
  float* bq = k5 + SLAB;                    // [6272,320]; reused as F (6.15MB)
  float* bk = bq + SLAB;                    // [6272,320]; reused as tabq+tabk
  float* aq = bk + SLAB;                    // [32,5,196]
  float* ak = aq + 32 * 5 * 196;            // [32,5,196]
  float* wpack = ak + 32 * 5 * 196;         // 5120+5120+1024 float4
  float4* Wq4 = (float4*)wpack;
  float4* Wk4 = Wq4 + 5120;
  float4* BW4 = Wk4 + 5120;
  float* F = bq;                            // [196,40,196] after k2
  float2* tabq = (float2*)bk;               // [32*40*196] float2
  float2* tabk = tabq + 32 * 40 * 196;

  k0w_pack<<<dim3(44), dim3(256), 0, stream>>>(lqw, lkw, base_w, Wq4, Wk4, BW4);
  k1_lin_base<<<dim3(2 * BHP / 8), dim3(320), 0, stream>>>(
      q, k, Wq4, lqb, Wk4, lkb, BW4, q5, k5, bq, bk);
  k2_act<<<dim3(62720 / 16), dim3(1024), 0, stream>>>(
      q5, bq, k5, bk, grid, coef_q, coef_k, scale_sp, scale_base, aq, ak);
  k2b_tab<<<dim3(501760 / 256), dim3(256), 0, stream>>>(
      aq, ak, grid_outer, tabq, tabk);
  k0_fuse<<<dim3(196), dim3(256), 0, stream>>>(coef_qk, cqo, F);
  k3_outer<<<dim3(6272 / 4), dim3(256), 0, stream>>>(tabq, tabk, F, out);
}

// Round 12
// 99.772 us; speedup vs baseline: 1.3432x; 1.1450x over previous
//
#include <hip/hip_runtime.h>
#include <math.h>

// Problem constants (B=4, H=8, P=196, D=64, NF=8, S=5)
#define BHP 6272   // B*H*P

// ---------------------------------------------------------------------------
// K0w: pack weights for coalesced k1 loads.
//   Wq4/Wk4[c4*320 + o] = float4(W[o][4c4..4c4+3]);  BW4[c4*64 + d] likewise.
// ---------------------------------------------------------------------------
__global__ __launch_bounds__(256) void k0w_pack(
    const float* __restrict__ Wq, const float* __restrict__ Wk,
    const float* __restrict__ BW, float4* __restrict__ Wq4,
    float4* __restrict__ Wk4, float4* __restrict__ BW4)
{
  const int e = blockIdx.x * 256 + threadIdx.x;  // [0, 11264)
  if (e < 5120) {
    const int o = e % 320, c4 = e / 320;
    Wq4[e] = *reinterpret_cast<const float4*>(Wq + o * 64 + c4 * 4);
  } else if (e < 10240) {
    const int e2 = e - 5120;
    const int o = e2 % 320, c4 = e2 / 320;
    Wk4[e2] = *reinterpret_cast<const float4*>(Wk + o * 64 + c4 * 4);
  } else if (e < 11264) {
    const int e2 = e - 10240;
    const int d = e2 % 64, c4 = e2 / 64;
    BW4[e2] = *reinterpret_cast<const float4*>(BW + d * 64 + c4 * 4);
  }
}

// ---------------------------------------------------------------------------
// K1 v3: weights preloaded into a register array (one vmcnt wait), explicit
// fmaf chains. 8 rows/block, 320 threads (thread = output col o).
// ---------------------------------------------------------------------------
__global__ __launch_bounds__(320) void k1_lin_base(
    const float* __restrict__ qx, const float* __restrict__ kx,
    const float4* __restrict__ Wq4, const float* __restrict__ bq_,
    const float4* __restrict__ Wk4, const float* __restrict__ bk_,
    const float4* __restrict__ BW4,
    float* __restrict__ y5q, float* __restrict__ y5k,
    float* __restrict__ baseq, float* __restrict__ basek)
{
  const bool kside = blockIdx.x >= (BHP / 8);
  const float* x = kside ? kx : qx;
  const float4* W4 = kside ? Wk4 : Wq4;
  const float* bias = kside ? bk_ : bq_;
  float* y5 = kside ? y5k : y5q;
  float* basef = kside ? basek : baseq;
  const int r0 = (kside ? blockIdx.x - BHP / 8 : blockIdx.x) * 8;

  __shared__ float xs[8][64];     // 2 KB
  __shared__ float sy[8][320];    // 10 KB
  const int t = threadIdx.x;
  for (int idx = t; idx < 8 * 64; idx += 320)
    xs[idx >> 6][idx & 63] = x[(size_t)(r0 + (idx >> 6)) * 64 + (idx & 63)];
  __syncthreads();

  const int o = t;
  float4 w[16];
  {
#pragma unroll
    for (int c4 = 0; c4 < 16; ++c4) w[c4] = W4[c4 * 320 + o];  // 16 b128, batched
    float acc[8];
#pragma unroll
    for (int rr = 0; rr < 8; ++rr) acc[rr] = 0.f;
#pragma unroll
    for (int c4 = 0; c4 < 16; ++c4) {
#pragma unroll
      for (int rr = 0; rr < 8; ++rr) {
        const float4 x4 = *reinterpret_cast<const float4*>(&xs[rr][c4 * 4]);
        acc[rr] = fmaf(x4.x, w[c4].x, acc[rr]);
        acc[rr] = fmaf(x4.y, w[c4].y, acc[rr]);
        acc[rr] = fmaf(x4.z, w[c4].z, acc[rr]);
        acc[rr] = fmaf(x4.w, w[c4].w, acc[rr]);
      }
    }
    const float bb = bias[o];
#pragma unroll
    for (int rr = 0; rr < 8; ++rr) {
      const float y = acc[rr] + bb;
      y5[(size_t)(r0 + rr) * 320 + o] = y;
      sy[rr][o] = y / (1.f + __expf(-y));        // silu
    }
  }
  __syncthreads();
  {
    const int s = o >> 6, d = o & 63;            // s uniform per wave
#pragma unroll
    for (int c4 = 0; c4 < 16; ++c4) w[c4] = BW4[c4 * 64 + d];
    float acc[8];
#pragma unroll
    for (int rr = 0; rr < 8; ++rr) acc[rr] = 0.f;
#pragma unroll
    for (int c4 = 0; c4 < 16; ++c4) {
#pragma unroll
      for (int rr = 0; rr < 8; ++rr) {
        const float4 x4 =
            *reinterpret_cast<const float4*>(&sy[rr][s * 64 + c4 * 4]);
        acc[rr] = fmaf(x4.x, w[c4].x, acc[rr]);
        acc[rr] = fmaf(x4.y, w[c4].y, acc[rr]);
        acc[rr] = fmaf(x4.z, w[c4].z, acc[rr]);
        acc[rr] = fmaf(x4.w, w[c4].w, acc[rr]);
      }
    }
#pragma unroll
    for (int rr = 0; rr < 8; ++rr)
      basef[(size_t)(r0 + rr) * 320 + o] = acc[rr];
  }
}

// ---------------------------------------------------------------------------
// K2 (q/k merged): one wave per (side, bh, s2, p2); lane=d. coef in LDS.
// Writes a[idx] = sum_d sigmoid(...).
// ---------------------------------------------------------------------------
__global__ __launch_bounds__(1024) void k2_act(
    const float* __restrict__ y5q, const float* __restrict__ bq,
    const float* __restrict__ y5k, const float* __restrict__ bk,
    const float* __restrict__ gridI,
    const float* __restrict__ cq, const float* __restrict__ ck,
    const float* __restrict__ ssp, const float* __restrict__ sbase,
    float* __restrict__ aq, float* __restrict__ ak)
{
  __shared__ float cl[40][65];   // 10.2 KB, coef as [m][d], pad 65
  __shared__ float gli[40];
  const int t = threadIdx.x;
  const int wave = t >> 6, lane = t & 63;
  const int gi = blockIdx.x * 16 + wave;       // [0, 62720); side-uniform/block
  const bool kside = gi >= 31360;
  const int idx = kside ? gi - 31360 : gi;

  {
    const float* coef = kside ? ck : cq;       // uniform within block
    for (int e = t; e < 2560; e += 1024) {
      const int d = e / 40, r = e % 40;        // coef flat = d*40 + f*5 + s
      const int f = r / 5, s = r % 5;
      cl[s * 8 + f][d] = coef[e];              // coalesced read
    }
    if (t < 40) gli[t] = gridI[t];
  }
  __syncthreads();

  const int p2 = idx % 196;
  const int s2 = (idx / 196) % 5;
  const int bh = idx / 980;
  const int h = bh & 7;
  const int d = lane;
  const int i0 = s2 * 196 + p2;
  const float* y5 = kside ? y5k : y5q;
  const float* basef = kside ? bk : bq;
  const float basev =
      basef[(size_t)(bh * 196 + i0 / 5) * 320 + (i0 % 5) * 64 + d];

  const int j0 = s2 * 1568 + p2;
  int p = j0 / 40;
  int m = j0 % 40;
  const float* y5b = y5 + (size_t)bh * 196 * 320 + d;
  float fv = 0.f;
#pragma unroll
  for (int f2 = 0; f2 < 8; ++f2) {
    const float g = gli[m];                        // LDS broadcast
    const float qv = y5b[p * 320 + (m >> 3) * 64]; // coalesced global
    fv = fmaf(__sinf(g * qv), cl[m][d], fv);       // LDS conflict-free
    p += 4; m += 36;
    if (m >= 40) { m -= 40; p += 1; }              // j += 196 carry
  }
  const int so = ((h * 5 + s2) * 196 + p2) * 64 + d;
  const float v = fv * ssp[so] + basev * sbase[so];
  float sg = 1.f / (1.f + __expf(-v));
#pragma unroll
  for (int off = 32; off > 0; off >>= 1) sg += __shfl_xor(sg, off);
  if (lane == 0) (kside ? ak : aq)[idx] = sg;
}

// ---------------------------------------------------------------------------
// K2b: dense sin/cos table fill, all 64 lanes active.
//   tab[bh*7840 + m*196 + p] = {sin(g_m * a), cos(g_m * a)}, g_m = m+1 integer.
//   Integer-g identity: sin(g*a) = sin(g*(a mod 2pi)); Cody-Waite 2-word.
// ---------------------------------------------------------------------------
__global__ __launch_bounds__(256) void k2b_tab(
    const float* __restrict__ aq, const float* __restrict__ ak,
    const float* __restrict__ go, float2* __restrict__ tq,
    float2* __restrict__ tk)
{
  const int n = blockIdx.x * 256 + threadIdx.x;   // [0, 501760)
  const bool kside = n >= 250880;
  const int i2 = kside ? n - 250880 : n;
  const int p = i2 % 196;
  const int m = (i2 / 196) % 40;
  const int bh = i2 / 7840;
  const float g = rintf(go[m]);                   // integers 1..40
  const float a = (kside ? ak : aq)[bh * 980 + (m >> 3) * 196 + p];
  // r = a mod 2pi, |r| <= pi (a in (0, ~64), n0 <= 11)
  const float n0 = rintf(a * 0.15915494309f);
  float r = fmaf(n0, -6.28318548f, a);            // 2pi_hi (f32 nearest)
  r = fmaf(n0, 1.74845553e-7f, r);                // 2pi_lo correction
  const float u = g * r;                          // |u| <= 126 rad
  float2* tab = kside ? tk : tq;
  tab[bh * 7840 + m * 196 + p] = make_float2(__sinf(u), __cosf(u));
}

// ---------------------------------------------------------------------------
// K0t: coefficient transpose + cqo fusion. One block per i.
//   F[i*7840 + (s*8+f)*196 + j] = cqk[(i*196+j)*40 + f*5+s] * cqo[(s*196+i)*196+j]
// ---------------------------------------------------------------------------
__global__ __launch_bounds__(256) void k0_fuse(
    const float* __restrict__ cqk, const float* __restrict__ cqo,
    float* __restrict__ F)
{
  const int i = blockIdx.x;             // [0,196)
  const int t = threadIdx.x;
  __shared__ float ld[196 * 41];        // [j][e], pad 41: 32.1 KB
  const float4* src = reinterpret_cast<const float4*>(cqk + (size_t)i * 7840);
  for (int e4 = t; e4 < 1960; e4 += 256) {
    const float4 v = src[e4];           // coalesced
    const int flat = e4 * 4;
    const int j = flat / 40, m0 = flat % 40;   // 40%4==0: no row straddle
    float* dst = &ld[j * 41 + m0];
    dst[0] = v.x; dst[1] = v.y; dst[2] = v.z; dst[3] = v.w;
  }
  __syncthreads();
  for (int e = t; e < 7840; e += 256) {
    const int mq = e / 196, j = e % 196;       // mq = s*8+f
    const int s = mq >> 3, f = mq & 7;
    const float val = ld[j * 41 + f * 5 + s];  // stride 41: conflict-free
    F[(size_t)i * 7840 + e] = val * cqo[(s * 196 + i) * 196 + j];
  }
}

// ---------------------------------------------------------------------------
// K3 v8: j-paired + dual-bh waves. block = (i, 8 bh: 2 per wave); F row i in
// LDS once; lane l owns j={2l,2l+1} and (l<34) j={128+2l,129+2l}.
// Per-row memory instrs: 80 VMEM b128 + 80 LDS (was 130 VMEM b64 + 200 LDS).
// Two independent bh load streams per wave for ILP. XCD swizzle: i-contiguous.
//   sin(g(aq+ak)) = sin(g aq)cos(g ak) + cos(g aq)sin(g ak)
// ---------------------------------------------------------------------------
__global__ __launch_bounds__(256) void k3_outer(
    const float2* __restrict__ tq, const float2* __restrict__ tk,
    const float* __restrict__ F, float* __restrict__ out)
{
  const int t = threadIdx.x;
  const int wave = t >> 6, lane = t & 63;
  // 784 blocks = 8 * 98; swz = (bid%8)*98 + bid/8 bijective.
  // XCD x gets swz in [98x, 98(x+1)) -> i contiguous ~24.5-range.
  const int bid = blockIdx.x;
  const int swz = (bid & 7) * 98 + (bid >> 3);
  const int i = swz >> 2;                  // [0,196)
  const int bhg = swz & 3;                 // [0,4): 8 bh each
  const int bh0 = bhg * 8 + wave * 2;      // this wave's two bh rows
  __shared__ float fs[7840];               // 31.4 KB: F row i, [m][j]
  __shared__ float2 sqs[8][40];            // 2.5 KB

  {
    const float4* Fp = reinterpret_cast<const float4*>(F + (size_t)i * 7840);
    float4* fs4 = reinterpret_cast<float4*>(fs);
    for (int e = t; e < 1960; e += 256) fs4[e] = Fp[e];   // coalesced
    for (int e = t; e < 320; e += 256) {
      const int bi = e / 40, mm = e % 40;
      sqs[bi][mm] = tq[(size_t)(bhg * 8 + bi) * 7840 + mm * 196 + i];
    }
  }
  __syncthreads();                          // the only barrier

  const bool hasb = lane < 34;              // pair-b lanes
  const int ja = 2 * lane;                  // j = ja, ja+1
  const int jb = hasb ? (128 + 2 * lane) : (2 * lane);  // clamped if masked
  const float2* tk0 = tk + (size_t)bh0 * 7840;
  const float2* tk1 = tk0 + 7840;
  const int w2 = wave * 2;

  float a0x = 0.f, a0y = 0.f, a1x = 0.f, a1y = 0.f;   // bh0: pair a, pair b
  float b0x = 0.f, b0y = 0.f, b1x = 0.f, b1y = 0.f;   // bh1
#pragma unroll 2
  for (int mm = 0; mm < 40; ++mm) {
    const int o = mm * 196;
    const float2 fa = *reinterpret_cast<const float2*>(&fs[o + ja]);
    const float2 fb = *reinterpret_cast<const float2*>(&fs[o + jb]);
    const float2 s0 = sqs[w2][mm];
    const float2 s1 = sqs[w2 + 1][mm];
    const float4 k0a = *reinterpret_cast<const float4*>(&tk0[o + ja]);
    const float4 k0b = *reinterpret_cast<const float4*>(&tk0[o + jb]);
    const float4 k1a = *reinterpret_cast<const float4*>(&tk1[o + ja]);
    const float4 k1b = *reinterpret_cast<const float4*>(&tk1[o + jb]);
    a0x = fmaf(fmaf(s0.x, k0a.y, s0.y * k0a.x), fa.x, a0x);
    a0y = fmaf(fmaf(s0.x, k0a.w, s0.y * k0a.z), fa.y, a0y);
    a1x = fmaf(fmaf(s0.x, k0b.y, s0.y * k0b.x), fb.x, a1x);
    a1y = fmaf(fmaf(s0.x, k0b.w, s0.y * k0b.z), fb.y, a1y);
    b0x = fmaf(fmaf(s1.x, k1a.y, s1.y * k1a.x), fa.x, b0x);
    b0y = fmaf(fmaf(s1.x, k1a.w, s1.y * k1a.z), fa.y, b0y);
    b1x = fmaf(fmaf(s1.x, k1b.y, s1.y * k1b.x), fb.x, b1x);
    b1y = fmaf(fmaf(s1.x, k1b.w, s1.y * k1b.z), fb.y, b1y);
  }

  // ---- softmax row bh0 (in-wave) ----
  {
    const float mB = hasb ? fmaxf(a1x, a1y) : -INFINITY;
    float mx = fmaxf(fmaxf(a0x, a0y), mB);
#pragma unroll
    for (int off = 32; off > 0; off >>= 1) mx = fmaxf(mx, __shfl_xor(mx, off));
    const float e0 = __expf(a0x - mx);
    const float e1 = __expf(a0y - mx);
    const float e2 = hasb ? __expf(a1x - mx) : 0.f;
    const float e3 = hasb ? __expf(a1y - mx) : 0.f;
    float ss = e0 + e1 + e2 + e3;
#pragma unroll
    for (int off = 32; off > 0; off >>= 1) ss += __shfl_xor(ss, off);
    const float inv = 1.f / ss;
    float2* op = reinterpret_cast<float2*>(out + (size_t)(bh0 * 196 + i) * 196);
    op[lane] = make_float2(e0 * inv, e1 * inv);
    if (hasb) op[64 + lane] = make_float2(e2 * inv, e3 * inv);
  }
  // ---- softmax row bh1 ----
  {
    const float mB = hasb ? fmaxf(b1x, b1y) : -INFINITY;
    float mx = fmaxf(fmaxf(b0x, b0y), mB);
#pragma unroll
    for (int off = 32; off > 0; off >>= 1) mx = fmaxf(mx, __shfl_xor(mx, off));
    const float e0 = __expf(b0x - mx);
    const float e1 = __expf(b0y - mx);
    const float e2 = hasb ? __expf(b1x - mx) : 0.f;
    const float e3 = hasb ? __expf(b1y - mx) : 0.f;
    float ss = e0 + e1 + e2 + e3;
#pragma unroll
    for (int off = 32; off > 0; off >>= 1) ss += __shfl_xor(ss, off);
    const float inv = 1.f / ss;
    float2* op =
        reinterpret_cast<float2*>(out + (size_t)((bh0 + 1) * 196 + i) * 196);
    op[lane] = make_float2(e0 * inv, e1 * inv);
    if (hasb) op[64 + lane] = make_float2(e2 * inv, e3 * inv);
  }
}

// ---------------------------------------------------------------------------
extern "C" void kernel_launch(void* const* d_in, const int* in_sizes, int n_in,
                              void* d_out, int out_size, void* d_ws, size_t ws_size,
                              hipStream_t stream) {
  const float* q          = (const float*)d_in[0];
  const float* k          = (const float*)d_in[1];
  const float* grid       = (const float*)d_in[3];
  const float* grid_outer = (const float*)d_in[4];
  const float* base_w     = (const float*)d_in[5];
  const float* coef_q     = (const float*)d_in[6];
  const float* coef_k     = (const float*)d_in[7];
  const float* coef_qk    = (const float*)d_in[8];
  const float* scale_base = (const float*)d_in[9];
  const float* scale_sp   = (const float*)d_in[10];
  const float* cqo        = (const float*)d_in[11];
  const float* lqw        = (const float*)d_in[12];
  const float* lqb        = (const float*)d_in[13];
  const float* lkw        = (const float*)d_in[14];
  const float* lkb        = (const float*)d_in[15];
  float* out = (float*)d_out;

  const size_t SLAB = (size_t)BHP * 320;    // 2,007,040 floats
  float* q5 = (float*)d_ws;                 // [6272,320]
  float* k5 = q5 + SLAB;                    // [6272,320]
  float* bq = k5 + SLAB;                    // [6272,320]; reused as F (6.15MB)
  float* bk = bq + SLAB;                    // [6272,320]; reused as tabq+tabk
  float* aq = bk + SLAB;                    // [32,5,196]
  float* ak = aq + 32 * 5 * 196;            // [32,5,196]
  float* wpack = ak + 32 * 5 * 196;         // 5120+5120+1024 float4
  float4* Wq4 = (float4*)wpack;
  float4* Wk4 = Wq4 + 5120;
  float4* BW4 = Wk4 + 5120;
  float* F = bq;                            // [196,40,196] after k2
  float2* tabq = (float2*)bk;               // [32*40*196] float2
  float2* tabk = tabq + 32 * 40 * 196;

  k0w_pack<<<dim3(44), dim3(256), 0, stream>>>(lqw, lkw, base_w, Wq4, Wk4, BW4);
  k1_lin_base<<<dim3(2 * BHP / 8), dim3(320), 0, stream>>>(
      q, k, Wq4, lqb, Wk4, lkb, BW4, q5, k5, bq, bk);
  k2_act<<<dim3(62720 / 16), dim3(1024), 0, stream>>>(
      q5, bq, k5, bk, grid, coef_q, coef_k, scale_sp, scale_base, aq, ak);
  k2b_tab<<<dim3(501760 / 256), dim3(256), 0, stream>>>(
      aq, ak, grid_outer, tabq, tabk);
  k0_fuse<<<dim3(196), dim3(256), 0, stream>>>(coef_qk, cqo, F);
  k3_outer<<<dim3(784), dim3(256), 0, stream>>>(tabq, tabk, F, out);
}